// Round 12
// baseline (320.421 us; speedup 1.0000x reference)
//
#include <hip/hip_runtime.h>
#include <math.h>

// Dims: V=50000 F=300 H=256 P=128 C=10  B=128 S=16 N=64  G=2048 T=131072

typedef unsigned short u16;
typedef __attribute__((ext_vector_type(8))) short bf16x8;
typedef __attribute__((ext_vector_type(4))) float f32x4;

__device__ __forceinline__ float b2f(u16 v){ return __uint_as_float(((unsigned)v)<<16); }
__device__ __forceinline__ u16 f2b(float f){
    unsigned u = __float_as_uint(f);
    return (u16)((u + 0x7FFFu + ((u>>16)&1u)) >> 16);   // RNE
}
__device__ __forceinline__ ushort4 pack4(float a,float b,float c,float d){
    ushort4 o; o.x=f2b(a); o.y=f2b(b); o.z=f2b(c); o.w=f2b(d); return o;
}

// Per-graph LDS region (64 KB): Srow (64 nodes x 256 feat bf16, XOR-swizzled)
// at 0..32767; Scol (256 feat x 64 nodes bf16, XOR-swizzled) at 32768..65535.
// Attention scratch (red[4][64], alpha[64]) aliases Scol (dead there).
// Block = 2 regions (128 KB): waves 0-3 -> graph A (region 0), 4-7 -> B.
#define SCOL_OFF 32768
__device__ __forceinline__ int srow_b(int nd, int f){
    return (nd*512 + f*2) ^ ((nd&7)<<4);
}
__device__ __forceinline__ int scol_b(int f, int nd){
    return SCOL_OFF + ((f*128 + nd*2) ^ ((f&7)<<4));
}
// weight fragment offset (u16 units) inside a (t, wave) pair of 1024-u16
// chunks: chunk-select (ni>>1)*1024, 16-col-half select (ni&1)*512.
__device__ __forceinline__ int wfrag_off(int ni){
    return ((ni>>1)<<10) + ((ni&1)<<9);
}

// ---------------------------------------------------------------------------
// Megakernel: 1024 blocks x 512 threads; each block = TWO graphs (one 64KB
// LDS region each). Wave w: graph q=w>>2, 64-wide feature slab (w&3)*64.
// Each SIMD hosts one A-wave + one B-wave -> independent streams; each
// weight chunk read serves both graphs (L2 weight traffic halved).
// Weight blobs: chunk (t*8+slab32)<<10 u16; elem [n_local]*32 + kk.
// launch_bounds(512,1): 256-reg cap. LDS=128KB already limits to 1 block/CU,
// so a tighter bound only forces spill (r11: (512,2) -> 128-reg cap ->
// 126 MB scratch WRITE_SIZE; r7: (512,6) -> 600 MB. Spill shows up as
// WRITE_SIZE >> output bytes).
// ---------------------------------------------------------------------------
__global__ __launch_bounds__(512, 1) void mega_k(
    const int* __restrict__ x, const u16* __restrict__ adjb,
    const u16* __restrict__ eprime,
    const u16* __restrict__ wb_w2a, const u16* __restrict__ wb_awa,
    const u16* __restrict__ wb_w1b, const u16* __restrict__ wb_w2b,
    const u16* __restrict__ wb_awb,
    const float* __restrict__ b1a, const float* __restrict__ b2a,
    const float* __restrict__ aba, const float* __restrict__ ava,
    const float* __restrict__ b1b, const float* __restrict__ b2b,
    const float* __restrict__ abb, const float* __restrict__ avb,
    u16* __restrict__ zb)
{
    __shared__ __align__(16) char sm[131072];
    const int tid = threadIdx.x;
    const int w = tid>>6, l = tid&63, lgp = l>>4, ll = l&15;
    const int q = w>>2, w4 = w&3, slab = w4*64;
    const long g = (long)blockIdx.x*2 + q;
    char* smq = sm + q*65536;
    const f32x4 zero4 = {0.f,0.f,0.f,0.f};

    // ---------------- S1: gather E'[x] rows for BOTH graphs -> Scol regions
    {
        const int r2 = tid >> 3;           // node 0..63
        const int fc = (tid & 7) * 32;     // 32-feature chunk
        #pragma unroll
        for (int q2=0; q2<2; ++q2){
            const u16* ep = eprime + (long)x[((long)blockIdx.x*2+q2)*64 + r2]*256 + fc;
            char* smr = sm + q2*65536;
            uint4 qa = *(const uint4*)(ep);
            uint4 qb = *(const uint4*)(ep + 8);
            uint4 qc = *(const uint4*)(ep + 16);
            uint4 qd = *(const uint4*)(ep + 24);
            #pragma unroll
            for (int qi=0; qi<4; ++qi){
                uint4 v = (qi==0)?qa:(qi==1)?qb:(qi==2)?qc:qd;
                unsigned xw[4] = {v.x, v.y, v.z, v.w};
                #pragma unroll
                for (int wi=0; wi<4; ++wi){
                    unsigned u = xw[wi];
                    int f0 = fc + qi*8 + wi*2;
                    *(u16*)(smr + scol_b(f0,   r2)) = (u16)(u & 0xffffu);
                    *(u16*)(smr + scol_b(f0+1, r2)) = (u16)(u >> 16);
                }
            }
        }
        __syncthreads();
    }

    const u16* adjg = adjb + g*4096;

    // ========== layer loop (two MP+att layers) ==========
    #pragma unroll 1
    for (int layer=0; layer<2; ++layer){
        const u16* wb_w2 = layer ? wb_w2b : wb_w2a;
        const u16* wb_aw = layer ? wb_awb : wb_awa;
        const float* b1  = layer ? b1b : b1a;
        const float* b2  = layer ? b2b : b2a;
        const float* ab  = layer ? abb : aba;
        const float* av  = layer ? avb : ava;
        const int zoff   = layer ? 512 : 0;

        // ---------- S2: T = relu(adj @ P + b1) : Scol -> Srow
        {
            f32x4 acc[4][4];
            #pragma unroll
            for (int i=0;i<4;++i){
                #pragma unroll
                for (int j=0;j<4;++j) acc[i][j] = zero4;
            }
            #pragma unroll
            for (int t=0;t<2;++t){
                const int k0 = t*32 + lgp*8;
                bf16x8 a[4], b[4];
                #pragma unroll
                for (int mi=0;mi<4;++mi)
                    a[mi] = *(const bf16x8*)(smq + scol_b(slab + mi*16 + ll, k0));
                #pragma unroll
                for (int ni=0;ni<4;++ni)
                    b[ni] = *(const bf16x8*)(adjg + (ni*16+ll)*64 + k0);
                #pragma unroll
                for (int mi=0;mi<4;++mi){
                    #pragma unroll
                    for (int ni=0;ni<4;++ni)
                        acc[mi][ni] = __builtin_amdgcn_mfma_f32_16x16x32_bf16(a[mi], b[ni], acc[mi][ni],0,0,0);
                }
            }
            #pragma unroll
            for (int mi=0;mi<4;++mi){
                int f0 = slab + mi*16 + lgp*4;
                float4 bi = *(const float4*)(b1 + f0);
                #pragma unroll
                for (int ni=0;ni<4;++ni){
                    int nd = ni*16 + ll;
                    f32x4 v = acc[mi][ni];
                    *(ushort4*)(smq + srow_b(nd, f0)) = pack4(
                        fmaxf(v[0]+bi.x,0.f), fmaxf(v[1]+bi.y,0.f),
                        fmaxf(v[2]+bi.z,0.f), fmaxf(v[3]+bi.w,0.f));
                }
            }
            __syncthreads();
        }

        // ---------- S3: H = relu(T @ w2 + b2) : Srow -> Srow (in-place)
        {
            f32x4 acc[4][4];
            #pragma unroll
            for (int i=0;i<4;++i){
                #pragma unroll
                for (int j=0;j<4;++j) acc[i][j] = zero4;
            }
            const u16* chw = wb_w2 + ((w4*2)<<10) + ll*32 + lgp*8;
            bf16x8 cw[4], nw[4];
            #pragma unroll
            for (int ni=0;ni<4;++ni) cw[ni] = *(const bf16x8*)(chw + wfrag_off(ni));
            #pragma unroll
            for (int t=0;t<8;++t){
                if (t < 7){
                    #pragma unroll
                    for (int ni=0;ni<4;++ni)
                        nw[ni] = *(const bf16x8*)(chw + (t+1)*8192 + wfrag_off(ni));
                }
                const int k0 = t*32 + lgp*8;
                bf16x8 b[4];
                #pragma unroll
                for (int ni=0;ni<4;++ni) b[ni] = *(const bf16x8*)(smq + srow_b(ni*16+ll, k0));
                #pragma unroll
                for (int mi=0;mi<4;++mi){
                    #pragma unroll
                    for (int ni=0;ni<4;++ni)
                        acc[mi][ni] = __builtin_amdgcn_mfma_f32_16x16x32_bf16(cw[mi], b[ni], acc[mi][ni],0,0,0);
                }
                if (t < 7){
                    #pragma unroll
                    for (int ni=0;ni<4;++ni) cw[ni] = nw[ni];
                }
            }
            __syncthreads();   // all waves done reading Srow before overwrite
            #pragma unroll
            for (int mi=0;mi<4;++mi){
                int f0 = slab + mi*16 + lgp*4;
                float4 bi = *(const float4*)(b2 + f0);
                #pragma unroll
                for (int ni=0;ni<4;++ni){
                    int nd = ni*16 + ll;
                    f32x4 v = acc[mi][ni];
                    *(ushort4*)(smq + srow_b(nd, f0)) = pack4(
                        fmaxf(v[0]+bi.x,0.f), fmaxf(v[1]+bi.y,0.f),
                        fmaxf(v[2]+bi.z,0.f), fmaxf(v[3]+bi.w,0.f));
                }
            }
            __syncthreads();
        }

        // ---------- S4: attention (U in registers; logits -> softmax -> pool)
        {
            f32x4 acc[4][4];
            #pragma unroll
            for (int i=0;i<4;++i){
                #pragma unroll
                for (int j=0;j<4;++j) acc[i][j] = zero4;
            }
            const u16* chw = wb_aw + ((w4*2)<<10) + ll*32 + lgp*8;
            bf16x8 cw[4], nw[4];
            #pragma unroll
            for (int ni=0;ni<4;++ni) cw[ni] = *(const bf16x8*)(chw + wfrag_off(ni));
            #pragma unroll
            for (int t=0;t<8;++t){
                if (t < 7){
                    #pragma unroll
                    for (int ni=0;ni<4;++ni)
                        nw[ni] = *(const bf16x8*)(chw + (t+1)*8192 + wfrag_off(ni));
                }
                const int k0 = t*32 + lgp*8;
                bf16x8 a[4];
                #pragma unroll
                for (int mi=0;mi<4;++mi) a[mi] = *(const bf16x8*)(smq + srow_b(mi*16+ll, k0));
                #pragma unroll
                for (int mi=0;mi<4;++mi){
                    #pragma unroll
                    for (int ni=0;ni<4;++ni)
                        acc[mi][ni] = __builtin_amdgcn_mfma_f32_16x16x32_bf16(a[mi], cw[ni], acc[mi][ni],0,0,0);
                }
                if (t < 7){
                    #pragma unroll
                    for (int ni=0;ni<4;++ni) cw[ni] = nw[ni];
                }
            }
            float abv[4], avv[4];
            #pragma unroll
            for (int ni=0;ni<4;++ni){
                int c = slab + ni*16 + ll;
                abv[ni] = ab[c]; avv[ni] = av[c];
            }
            float lgt[4][4];
            #pragma unroll
            for (int mi=0;mi<4;++mi){
                #pragma unroll
                for (int r=0;r<4;++r) lgt[mi][r] = 0.f;
            }
            #pragma unroll
            for (int mi=0;mi<4;++mi){
                #pragma unroll
                for (int ni=0;ni<4;++ni){
                    f32x4 v = acc[mi][ni];
                    #pragma unroll
                    for (int r=0;r<4;++r) lgt[mi][r] += fmaxf(v[r]+abv[ni],0.f)*avv[ni];
                }
            }
            #pragma unroll
            for (int mi=0;mi<4;++mi){
                #pragma unroll
                for (int r=0;r<4;++r){
                    float vv = lgt[mi][r];
                    vv += __shfl_xor(vv,1,64); vv += __shfl_xor(vv,2,64);
                    vv += __shfl_xor(vv,4,64); vv += __shfl_xor(vv,8,64);
                    lgt[mi][r] = vv;
                }
            }
            float* red = (float*)(smq + SCOL_OFF);
            if (ll == 0){
                #pragma unroll
                for (int mi=0;mi<4;++mi){
                    #pragma unroll
                    for (int r=0;r<4;++r){
                        int node = mi*16 + lgp*4 + r;
                        red[w4*64 + node] = lgt[mi][r];
                    }
                }
            }
            __syncthreads();
            if (tid < 128){
                int qs = tid >> 6, t64 = tid & 63;
                const float* rq = (const float*)(sm + qs*65536 + SCOL_OFF);
                float lv = rq[t64] + rq[64+t64] + rq[128+t64] + rq[192+t64];
                float v = (t64 < 63) ? lv : -INFINITY;
                float m = v;
                #pragma unroll
                for (int off=32; off; off>>=1) m = fmaxf(m, __shfl_xor(m, off, 64));
                float e = (t64 < 63) ? expf(v - m) : 0.f;
                float s = e;
                #pragma unroll
                for (int off=32; off; off>>=1) s += __shfl_xor(s, off, 64);
                *(float*)(sm + qs*65536 + SCOL_OFF + 1024 + t64*4) = e / s;
            }
            __syncthreads();
            {
                int qs = tid >> 8, c = tid & 255;
                char* smr = sm + qs*65536;
                const float* alpha = (const float*)(smr + SCOL_OFF + 1024);
                float pool = 0.f;
                for (int r=0;r<63;++r)
                    pool += alpha[r]*b2f(*(const u16*)(smr + srow_b(r,c)));
                long zb0 = ((long)blockIdx.x*2 + qs)*1024 + zoff;
                zb[zb0 + c]       = f2b(pool);
                zb[zb0 + 256 + c] = *(const u16*)(smr + srow_b(63,c));
            }
            __syncthreads();
        }

        // ---------- S5 (layer 0 only): P1 = H1 @ w1b : Srow -> Scol
        if (layer == 0){
            f32x4 acc[4][4];
            #pragma unroll
            for (int i=0;i<4;++i){
                #pragma unroll
                for (int j=0;j<4;++j) acc[i][j] = zero4;
            }
            const u16* chw = wb_w1b + ((w4*2)<<10) + ll*32 + lgp*8;
            bf16x8 cw[4], nw[4];
            #pragma unroll
            for (int ni=0;ni<4;++ni) cw[ni] = *(const bf16x8*)(chw + wfrag_off(ni));
            #pragma unroll
            for (int t=0;t<8;++t){
                if (t < 7){
                    #pragma unroll
                    for (int ni=0;ni<4;++ni)
                        nw[ni] = *(const bf16x8*)(chw + (t+1)*8192 + wfrag_off(ni));
                }
                const int k0 = t*32 + lgp*8;
                bf16x8 a[4];
                #pragma unroll
                for (int mi=0;mi<4;++mi) a[mi] = *(const bf16x8*)(smq + srow_b(mi*16+ll, k0));
                #pragma unroll
                for (int mi=0;mi<4;++mi){
                    #pragma unroll
                    for (int ni=0;ni<4;++ni)
                        acc[mi][ni] = __builtin_amdgcn_mfma_f32_16x16x32_bf16(a[mi], cw[ni], acc[mi][ni],0,0,0);
                }
                if (t < 7){
                    #pragma unroll
                    for (int ni=0;ni<4;++ni) cw[ni] = nw[ni];
                }
            }
            __syncthreads();   // softmax-scratch reads done before Scol overwrite
            #pragma unroll
            for (int mi=0;mi<4;++mi){
                #pragma unroll
                for (int ni=0;ni<4;++ni){
                    int fo = slab + ni*16 + ll, nd0 = mi*16 + lgp*4;
                    f32x4 v = acc[mi][ni];
                    *(ushort4*)(smq + scol_b(fo,nd0)) = pack4(v[0],v[1],v[2],v[3]);
                }
            }
            __syncthreads();
        }
    }
}

// ---------------------------------------------------------------------------
// E' = emb @ w1a  (50000x300 @ 300x256 -> bf16 50000x256 row-major).
// ---------------------------------------------------------------------------
__global__ __launch_bounds__(256) void eprime_k(
    const float* __restrict__ emb, const u16* __restrict__ blob,
    u16* __restrict__ eprime)
{
    __shared__ __align__(16) char sm[4096];     // 2 x 2KB A-tile dbuf
    const int h = blockIdx.x, m0 = blockIdx.y * 32;
    const int tid = threadIdx.x;
    const int w = tid>>6, l = tid&63, lgp = l>>4, ll = l&15;
    const f32x4 zero4 = {0.f,0.f,0.f,0.f};
    const int slab = h*4 + w;

    const int r  = tid >> 3;          // row 0..31
    const int kc = (tid & 7) * 4;     // k-chunk (floats) within 32
    int rowg = m0 + r; if (rowg > 49999) rowg = 49999;
    const long arow = (long)rowg * 300;
    const int wbyte = (r*64 + (tid&7)*8) ^ ((r&7)<<4);

    float4 pv = (kc + 4 <= 300) ? *(const float4*)(emb + arow + kc)
                                : make_float4(0.f,0.f,0.f,0.f);
    const u16* chw = blob + (slab<<10) + ll*32 + lgp*8;
    bf16x8 w0 = *(const bf16x8*)(chw);
    bf16x8 w1 = *(const bf16x8*)(chw + 512);

    f32x4 acc[2][2];
    acc[0][0]=zero4; acc[0][1]=zero4; acc[1][0]=zero4; acc[1][1]=zero4;

    #pragma unroll
    for (int t=0;t<10;++t){
        float4 cur = pv;
        bf16x8 cw0 = w0, cw1 = w1;
        if (t < 9){
            int kn = (t+1)*32 + kc;
            pv = (kn + 4 <= 300) ? *(const float4*)(emb + arow + kn)
                                 : make_float4(0.f,0.f,0.f,0.f);
            const u16* nx = chw + (t+1)*8192;
            w0 = *(const bf16x8*)(nx);
            w1 = *(const bf16x8*)(nx + 512);
        }
        *(ushort4*)(sm + (t&1)*2048 + wbyte) = pack4(cur.x,cur.y,cur.z,cur.w);
        __syncthreads();
        const char* eb = sm + (t&1)*2048;
        bf16x8 a0, a1;
        {
            int row = ll;
            a0 = *(const bf16x8*)(eb + ((row*64 + lgp*16) ^ ((row&7)<<4)));
            row = 16 + ll;
            a1 = *(const bf16x8*)(eb + ((row*64 + lgp*16) ^ ((row&7)<<4)));
        }
        acc[0][0] = __builtin_amdgcn_mfma_f32_16x16x32_bf16(a0, cw0, acc[0][0],0,0,0);
        acc[0][1] = __builtin_amdgcn_mfma_f32_16x16x32_bf16(a0, cw1, acc[0][1],0,0,0);
        acc[1][0] = __builtin_amdgcn_mfma_f32_16x16x32_bf16(a1, cw0, acc[1][0],0,0,0);
        acc[1][1] = __builtin_amdgcn_mfma_f32_16x16x32_bf16(a1, cw1, acc[1][1],0,0,0);
        __syncthreads();
    }
    #pragma unroll
    for (int mi=0;mi<2;++mi){
        #pragma unroll
        for (int ni=0;ni<2;++ni){
            int col = h*128 + w*32 + ni*16 + ll;
            f32x4 v = acc[mi][ni];
            #pragma unroll
            for (int rr=0;rr<4;++rr){
                int row = m0 + mi*16 + lgp*4 + rr;
                if (row < 50000) eprime[(long)row*256 + col] = f2b(v[rr]);
            }
        }
    }
}

// ---------------------------------------------------------------------------
// Weight pre-pass: 6 GEMM weights -> bf16 8-slab K-tiled blobs (zero-pad K).
// ---------------------------------------------------------------------------
__global__ __launch_bounds__(256) void conv_all_k(
    const float* __restrict__ w1a, const float* __restrict__ w2a,
    const float* __restrict__ awa, const float* __restrict__ w1b,
    const float* __restrict__ w2b, const float* __restrict__ awb,
    u16* __restrict__ dst_base)
{
    long idx = (long)blockIdx.x*256 + threadIdx.x;
    if (idx >= 81920L + 5L*65536L) return;
    const float* src; u16* dst; int Ksrc; long rem;
    if (idx < 81920L){ src = w1a; dst = dst_base; Ksrc = 300; rem = idx; }
    else {
        long j = (idx - 81920L) / 65536L, r2 = (idx - 81920L) % 65536L;
        src = (j==0)?w2a:(j==1)?awa:(j==2)?w1b:(j==3)?w2b:awb;
        dst = dst_base + 81920L + j*65536L; Ksrc = 256; rem = r2;
    }
    int k = (int)(rem >> 8), n = (int)(rem & 255);
    float v = (k < Ksrc) ? src[k*256 + n] : 0.f;
    int t = k>>5, kk = k&31;
    dst[((t*8 + (n>>5))<<10) + (n&31)*32 + kk] = f2b(v);
}

// adj f32 -> bf16 (linear copy)
__global__ __launch_bounds__(256) void adjconv_k(
    const float* __restrict__ adj, u16* __restrict__ adjb)
{
    long i = (long)blockIdx.x*256 + threadIdx.x;
    if (i < 2048L*4096L) adjb[i] = f2b(adj[i]);
}

// ---------------------------------------------------------------------------
// BatchNorm stats over rows of zb (2048 x 1024 bf16): scale/shift per column.
// ---------------------------------------------------------------------------
__global__ __launch_bounds__(256) void bnstats_k(
    const u16* __restrict__ zb, const float* __restrict__ gamma,
    const float* __restrict__ beta,
    float* __restrict__ scale, float* __restrict__ shift)
{
    const int tid = threadIdx.x;
    const int cl = tid & 3, ph = tid >> 2;
    const int c = blockIdx.x * 4 + cl;
    double s = 0.0, s2 = 0.0;
    #pragma unroll 8
    for (int r = ph; r < 2048; r += 64) {
        float v = b2f(zb[(long)r * 1024 + c]);
        s += v; s2 += (double)v * v;
    }
    __shared__ double ss[256], ss2[256];
    ss[tid] = s; ss2[tid] = s2;
    __syncthreads();
    for (int off = 128; off >= 4; off >>= 1){
        if (tid < off){ ss[tid] += ss[tid+off]; ss2[tid] += ss2[tid+off]; }
        __syncthreads();
    }
    if (tid < 4){
        int cc = blockIdx.x * 4 + tid;
        double mu = ss[tid] / 2048.0;
        double var = ss2[tid] / 2048.0 - mu * mu;
        float inv = (float)(1.0 / sqrt(var + 1e-5));
        float sc = gamma[cc] * inv;
        scale[cc] = sc;
        shift[cc] = beta[cc] - (float)mu * sc;
    }
}

// fc1 weight blob: W'[k][n] = scale[k]*fc1_w[k][n] -> 8-slab K-tiled bf16
__global__ __launch_bounds__(256) void wconv_fc1_k(
    const float* __restrict__ fw, const float* __restrict__ scale,
    u16* __restrict__ dst)
{
    int lin = blockIdx.x*256 + threadIdx.x;           // 262144 total
    int c = lin >> 10, t = c >> 3, s = c & 7;
    int nl = (lin >> 5) & 31, kk = lin & 31;
    int n = s*32 + nl, k = t*32 + kk;
    dst[lin] = f2b(fw[k*256 + n] * scale[k]);
}

// fc1 bias': biasp[n] = fc1_b[n] + sum_k shift[k]*fc1_w[k][n]
__global__ __launch_bounds__(256) void fusefc1_k(
    const float* __restrict__ fw, const float* __restrict__ shift,
    const float* __restrict__ fb, float* __restrict__ biasp)
{
    const int n = blockIdx.x, tid = threadIdx.x;
    float p = 0.f;
    #pragma unroll
    for (int i=0;i<4;++i){
        int k = tid + i*256;
        p += shift[k] * fw[k*256 + n];
    }
    __shared__ float red[256];
    red[tid] = p;
    __syncthreads();
    for (int off=128; off; off>>=1){
        if (tid < off) red[tid] += red[tid+off];
        __syncthreads();
    }
    if (tid == 0) biasp[n] = fb[n] + red[0];
}

// ---------------------------------------------------------------------------
// fc1 MFMA: z2 = relu(zb @ W' + biasp)  (2048x1024 @ 1024x256, bn absorbed)
// ---------------------------------------------------------------------------
__global__ __launch_bounds__(256) void fc1_mfma_k(
    const u16* __restrict__ zb, const u16* __restrict__ blob,
    const float* __restrict__ biasp, float* __restrict__ z2)
{
    __shared__ __align__(16) char sm[4096];     // 2 x 2KB A-tile dbuf
    const int h = blockIdx.x, m0 = blockIdx.y * 32;
    const int tid = threadIdx.x;
    const int w = tid>>6, l = tid&63, lgp = l>>4, ll = l&15;
    const f32x4 zero4 = {0.f,0.f,0.f,0.f};
    const int slab = h*4 + w;

    const int r  = tid >> 3;          // row 0..31
    const int kc = (tid & 7) * 4;     // k-chunk within 32
    const long arow = (long)(m0 + r) * 1024;
    const int wbyte = (r*64 + (tid&7)*8) ^ ((r&7)<<4);

    ushort4 pv = *(const ushort4*)(zb + arow + kc);
    const u16* chw = blob + (slab<<10) + ll*32 + lgp*8;
    bf16x8 w0 = *(const bf16x8*)(chw);
    bf16x8 w1 = *(const bf16x8*)(chw + 512);

    f32x4 acc[2][2];
    acc[0][0]=zero4; acc[0][1]=zero4; acc[1][0]=zero4; acc[1][1]=zero4;

    #pragma unroll 4
    for (int t=0;t<32;++t){
        ushort4 cur = pv;
        bf16x8 cw0 = w0, cw1 = w1;
        if (t < 31){
            pv = *(const ushort4*)(zb + arow + (t+1)*32 + kc);
            const u16* nx = chw + (t+1)*8192;
            w0 = *(const bf16x8*)(nx);
            w1 = *(const bf16x8*)(nx + 512);
        }
        *(ushort4*)(sm + (t&1)*2048 + wbyte) = cur;
        __syncthreads();
        const char* eb = sm + (t&1)*2048;
        bf16x8 a0, a1;
        {
            int row = ll;
            a0 = *(const bf16x8*)(eb + ((row*64 + lgp*16) ^ ((row&7)<<4)));
            row = 16 + ll;
            a1 = *(const bf16x8*)(eb + ((row*64 + lgp*16) ^ ((row&7)<<4)));
        }
        acc[0][0] = __builtin_amdgcn_mfma_f32_16x16x32_bf16(a0, cw0, acc[0][0],0,0,0);
        acc[0][1] = __builtin_amdgcn_mfma_f32_16x16x32_bf16(a0, cw1, acc[0][1],0,0,0);
        acc[1][0] = __builtin_amdgcn_mfma_f32_16x16x32_bf16(a1, cw0, acc[1][0],0,0,0);
        acc[1][1] = __builtin_amdgcn_mfma_f32_16x16x32_bf16(a1, cw1, acc[1][1],0,0,0);
        __syncthreads();
    }
    #pragma unroll
    for (int mi=0;mi<2;++mi){
        #pragma unroll
        for (int ni=0;ni<2;++ni){
            int col = h*128 + w*32 + ni*16 + ll;
            float bv = biasp[col];
            f32x4 v = acc[mi][ni];
            #pragma unroll
            for (int rr=0;rr<4;++rr){
                int row = m0 + mi*16 + lgp*4 + rr;
                z2[(long)row*256 + col] = fmaxf(v[rr] + bv, 0.f);
            }
        }
    }
}

// ---------------------------------------------------------------------------
// Segment attention + final head fused:
// z2 (128 x 16 x 256) -> pooled -> relu(@fc2+b2) -> @fc3+b3 -> log_softmax
// ---------------------------------------------------------------------------
__global__ __launch_bounds__(256) void sattfinal_k(
    const float* __restrict__ z2, const float* __restrict__ sw,
    const float* __restrict__ sb, const float* __restrict__ sv,
    const float* __restrict__ w2, const float* __restrict__ b2,
    const float* __restrict__ w3, const float* __restrict__ b3,
    float* __restrict__ out)
{
    const int b = blockIdx.x;
    const int tid = threadIdx.x;
    __shared__ float zs[16][256];
    for (int idx = tid; idx < 16 * 256; idx += 256) {
        int r = idx >> 8, c = idx & 255;
        zs[r][c] = z2[((long)b * 16 + r) * 256 + c];
    }
    __syncthreads();

    float acc[16] = {};
    for (int k = 0; k < 256; ++k) {
        float w = sw[k * 256 + tid];
        #pragma unroll
        for (int r = 0; r < 16; ++r) acc[r] += zs[r][k] * w;
    }
    const float sbv = sb[tid], svv = sv[tid];

    __shared__ float red[16][4];
    __shared__ float logit_s[16], alpha_s[16];
    const int warp = tid >> 6, lane = tid & 63;
    #pragma unroll
    for (int r = 0; r < 16; ++r) {
        float u = fmaxf(acc[r] + sbv, 0.f);
        float lv = u * svv;
        #pragma unroll
        for (int off = 32; off; off >>= 1) lv += __shfl_down(lv, off, 64);
        if (lane == 0) red[r][warp] = lv;
    }
    __syncthreads();
    if (tid < 16) logit_s[tid] = red[tid][0] + red[tid][1] + red[tid][2] + red[tid][3];
    __syncthreads();
    if (tid < 16) {
        float m = -INFINITY;
        #pragma unroll
        for (int i = 0; i < 16; ++i) m = fmaxf(m, logit_s[i]);
        float ssum = 0.f;
        #pragma unroll
        for (int i = 0; i < 16; ++i) ssum += expf(logit_s[i] - m);
        alpha_s[tid] = expf(logit_s[tid] - m) / ssum;
    }
    __syncthreads();
    float pacc = 0.f;
    #pragma unroll
    for (int r = 0; r < 16; ++r) pacc += alpha_s[r] * zs[r][tid];

    __shared__ float ps[256], z3s[128], z4s[10];
    ps[tid] = pacc;
    __syncthreads();
    if (tid < 128){
        float a2 = b2[tid];
        for (int k = 0; k < 256; ++k) a2 += ps[k] * w2[k * 128 + tid];
        z3s[tid] = fmaxf(a2, 0.f);
    }
    __syncthreads();
    if (tid < 10){
        float a3 = b3[tid];
        for (int k = 0; k < 128; ++k) a3 += z3s[k] * w3[k * 10 + tid];
        z4s[tid] = a3;
    }
    __syncthreads();
    if (tid < 10){
        float m = z4s[0];
        #pragma unroll
        for (int i = 1; i < 10; ++i) m = fmaxf(m, z4s[i]);
        float s = 0.f;
        #pragma unroll
        for (int i = 0; i < 10; ++i) s += expf(z4s[i] - m);
        out[b * 10 + tid] = z4s[tid] - m - logf(s);
    }
}

// ---------------------------------------------------------------------------
extern "C" void kernel_launch(void* const* d_in, const int* in_sizes, int n_in,
                              void* d_out, int out_size, void* d_ws, size_t ws_size,
                              hipStream_t stream)
{
    const int*   x      = (const int*)d_in[0];
    const float* adj    = (const float*)d_in[1];
    // d_in[2] = adj_s (unused), d_in[3]/d_in[4] = shape scalars
    const float* emb    = (const float*)d_in[5];
    const float* mp0_w1 = (const float*)d_in[6];
    const float* mp0_b1 = (const float*)d_in[7];
    const float* mp0_w2 = (const float*)d_in[8];
    const float* mp0_b2 = (const float*)d_in[9];
    const float* mp1_w1 = (const float*)d_in[10];
    const float* mp1_b1 = (const float*)d_in[11];
    const float* mp1_w2 = (const float*)d_in[12];
    const float* mp1_b2 = (const float*)d_in[13];
    const float* att0_w = (const float*)d_in[14];
    const float* att0_b = (const float*)d_in[15];
    const float* att0_v = (const float*)d_in[16];
    const float* att1_w = (const float*)d_in[17];
    const float* att1_b = (const float*)d_in[18];
    const float* att1_v = (const float*)d_in[19];
    const float* bn_g   = (const float*)d_in[20];
    const float* bn_b   = (const float*)d_in[21];
    const float* fc1_w  = (const float*)d_in[22];
    const float* fc1_b  = (const float*)d_in[23];
    const float* satt_w = (const float*)d_in[24];
    const float* satt_b = (const float*)d_in[25];
    const float* satt_v = (const float*)d_in[26];
    const float* fc2_w  = (const float*)d_in[27];
    const float* fc2_b  = (const float*)d_in[28];
    const float* fc3_w  = (const float*)d_in[29];
    const float* fc3_b  = (const float*)d_in[30];
    float* out = (float*)d_out;

    float* ws = (float*)d_ws;
    float* z2      = ws;                    // 2048*256 f32
    float* scale   = z2 + 2048L * 256;      // 1024
    float* shiftv  = scale + 1024;          // 1024
    float* biasp   = shiftv + 1024;         // 256
    u16*   wbase   = (u16*)(biasp + 256);
    u16* wb_w1a  = wbase;                   // 81920 u16 (K=320 tiled)
    u16* wb_w2a  = wb_w1a + 81920;          // 65536 each below
    u16* wb_awa  = wb_w2a + 65536;
    u16* wb_w1b  = wb_awa + 65536;
    u16* wb_w2b  = wb_w1b + 65536;
    u16* wb_awb  = wb_w2b + 65536;
    u16* adjb    = wb_awb + 65536;          // 2048*4096 u16 (16.8 MB)
    u16* zb      = adjb + 2048L*4096;       // 2048*1024 u16 (4.2 MB)
    u16* fc1blob = zb + 2048L*1024;         // 262144 u16
    u16* eprime  = fc1blob + 262144;        // 50048*256 u16 (25.6 MB)
    // total ws ~ 50 MB

    conv_all_k<<<dim3(1600), dim3(256), 0, stream>>>(
        mp0_w1, mp0_w2, att0_w, mp1_w1, mp1_w2, att1_w, wbase);
    adjconv_k<<<dim3(32768), dim3(256), 0, stream>>>(adj, adjb);
    eprime_k<<<dim3(2, 1563), dim3(256), 0, stream>>>(emb, wb_w1a, eprime);

    mega_k<<<dim3(1024), dim3(512), 0, stream>>>(
        x, adjb, eprime,
        wb_w2a, wb_awa, wb_w1b, wb_w2b, wb_awb,
        mp0_b1, mp0_b2, att0_b, att0_v,
        mp1_b1, mp1_b2, att1_b, att1_v, zb);

    bnstats_k<<<dim3(256), dim3(256), 0, stream>>>(zb, bn_g, bn_b, scale, shiftv);
    wconv_fc1_k<<<dim3(1024), dim3(256), 0, stream>>>(fc1_w, scale, fc1blob);
    fusefc1_k<<<dim3(256), dim3(256), 0, stream>>>(fc1_w, shiftv, fc1_b, biasp);
    fc1_mfma_k<<<dim3(2, 64), dim3(256), 0, stream>>>(zb, fc1blob, biasp, z2);
    sattfinal_k<<<dim3(128), dim3(256), 0, stream>>>(z2, satt_w, satt_b, satt_v,
        fc2_w, fc2_b, fc3_w, fc3_b, out);
}

// Round 13
// 311.445 us; speedup vs baseline: 1.0288x; 1.0288x over previous
//
#include <hip/hip_runtime.h>
#include <math.h>

// Dims: V=50000 F=300 H=256 P=128 C=10  B=128 S=16 N=64  G=2048 T=131072

typedef unsigned short u16;
typedef __attribute__((ext_vector_type(8))) short bf16x8;
typedef __attribute__((ext_vector_type(4))) float f32x4;

__device__ __forceinline__ float b2f(u16 v){ return __uint_as_float(((unsigned)v)<<16); }
__device__ __forceinline__ u16 f2b(float f){
    unsigned u = __float_as_uint(f);
    return (u16)((u + 0x7FFFu + ((u>>16)&1u)) >> 16);   // RNE
}
__device__ __forceinline__ ushort4 pack4(float a,float b,float c,float d){
    ushort4 o; o.x=f2b(a); o.y=f2b(b); o.z=f2b(c); o.w=f2b(d); return o;
}

// Per-graph LDS region (64 KB): Srow (64 nodes x 256 feat bf16, XOR-swizzled)
// at 0..32767; Scol (256 feat x 64 nodes bf16, XOR-swizzled) at 32768..65535.
// Attention scratch (red[4][64], alpha[64]) aliases Scol (dead there).
// Block = 2 regions (128 KB): waves 0-3 -> graph A (region 0), 4-7 -> B.
#define SCOL_OFF 32768
__device__ __forceinline__ int srow_b(int nd, int f){
    return (nd*512 + f*2) ^ ((nd&7)<<4);
}
__device__ __forceinline__ int scol_b(int f, int nd){
    return SCOL_OFF + ((f*128 + nd*2) ^ ((f&7)<<4));
}
// weight fragment offset (u16 units): chunk-select (ni>>1)*1024,
// 16-col-half select (ni&1)*512.
__device__ __forceinline__ int wfrag_off(int ni){
    return ((ni>>1)<<10) + ((ni&1)<<9);
}

// ---------------------------------------------------------------------------
// Megakernel: 1024 blocks x 512 threads; each block = TWO graphs (one 64KB
// LDS region each). Wave w: graph q=w>>2, 64-wide feature slab (w&3)*64.
// Weight blobs: chunk (t*8+slab32)<<10 u16; elem [n_local]*32 + kk.
// Register strategy (r11/r12 lesson): allocator pinned 128 VGPR -> 120MB
// scratch spill. Fix: (1) amdgpu_waves_per_eu(1,2) raises the cap to 256
// (LDS=128KB limits to 1 block/CU = 2 waves/EU anyway); (2) no manual
// weight-prefetch registers -- the t-loops are barrier-free, compiler
// pipelines the inline loads itself.
// ---------------------------------------------------------------------------
__global__ __attribute__((amdgpu_flat_work_group_size(512,512),
                          amdgpu_waves_per_eu(1,2)))
void mega_k(
    const int* __restrict__ x, const u16* __restrict__ adjb,
    const u16* __restrict__ eprime,
    const u16* __restrict__ wb_w2a, const u16* __restrict__ wb_awa,
    const u16* __restrict__ wb_w1b, const u16* __restrict__ wb_w2b,
    const u16* __restrict__ wb_awb,
    const float* __restrict__ b1a, const float* __restrict__ b2a,
    const float* __restrict__ aba, const float* __restrict__ ava,
    const float* __restrict__ b1b, const float* __restrict__ b2b,
    const float* __restrict__ abb, const float* __restrict__ avb,
    u16* __restrict__ zb)
{
    __shared__ __align__(16) char sm[131072];
    const int tid = threadIdx.x;
    const int w = tid>>6, l = tid&63, lgp = l>>4, ll = l&15;
    const int q = w>>2, w4 = w&3, slab = w4*64;
    const long g = (long)blockIdx.x*2 + q;
    char* smq = sm + q*65536;
    const f32x4 zero4 = {0.f,0.f,0.f,0.f};

    // ---------------- S1: gather E'[x] rows for BOTH graphs -> Scol regions
    {
        const int r2 = tid >> 3;           // node 0..63
        const int fc = (tid & 7) * 32;     // 32-feature chunk
        #pragma unroll
        for (int q2=0; q2<2; ++q2){
            const u16* ep = eprime + (long)x[((long)blockIdx.x*2+q2)*64 + r2]*256 + fc;
            char* smr = sm + q2*65536;
            uint4 qa = *(const uint4*)(ep);
            uint4 qb = *(const uint4*)(ep + 8);
            uint4 qc = *(const uint4*)(ep + 16);
            uint4 qd = *(const uint4*)(ep + 24);
            #pragma unroll
            for (int qi=0; qi<4; ++qi){
                uint4 v = (qi==0)?qa:(qi==1)?qb:(qi==2)?qc:qd;
                unsigned xw[4] = {v.x, v.y, v.z, v.w};
                #pragma unroll
                for (int wi=0; wi<4; ++wi){
                    unsigned u = xw[wi];
                    int f0 = fc + qi*8 + wi*2;
                    *(u16*)(smr + scol_b(f0,   r2)) = (u16)(u & 0xffffu);
                    *(u16*)(smr + scol_b(f0+1, r2)) = (u16)(u >> 16);
                }
            }
        }
        __syncthreads();
    }

    const u16* adjg = adjb + g*4096;

    // ========== layer loop (two MP+att layers) ==========
    #pragma unroll 1
    for (int layer=0; layer<2; ++layer){
        const u16* wb_w2 = layer ? wb_w2b : wb_w2a;
        const u16* wb_aw = layer ? wb_awb : wb_awa;
        const float* b1  = layer ? b1b : b1a;
        const float* b2  = layer ? b2b : b2a;
        const float* ab  = layer ? abb : aba;
        const float* av  = layer ? avb : ava;
        const int zoff   = layer ? 512 : 0;

        // ---------- S2: T = relu(adj @ P + b1) : Scol -> Srow
        {
            f32x4 acc[4][4];
            #pragma unroll
            for (int i=0;i<4;++i){
                #pragma unroll
                for (int j=0;j<4;++j) acc[i][j] = zero4;
            }
            #pragma unroll
            for (int t=0;t<2;++t){
                const int k0 = t*32 + lgp*8;
                bf16x8 a[4], b[4];
                #pragma unroll
                for (int mi=0;mi<4;++mi)
                    a[mi] = *(const bf16x8*)(smq + scol_b(slab + mi*16 + ll, k0));
                #pragma unroll
                for (int ni=0;ni<4;++ni)
                    b[ni] = *(const bf16x8*)(adjg + (ni*16+ll)*64 + k0);
                #pragma unroll
                for (int mi=0;mi<4;++mi){
                    #pragma unroll
                    for (int ni=0;ni<4;++ni)
                        acc[mi][ni] = __builtin_amdgcn_mfma_f32_16x16x32_bf16(a[mi], b[ni], acc[mi][ni],0,0,0);
                }
            }
            #pragma unroll
            for (int mi=0;mi<4;++mi){
                int f0 = slab + mi*16 + lgp*4;
                float4 bi = *(const float4*)(b1 + f0);
                #pragma unroll
                for (int ni=0;ni<4;++ni){
                    int nd = ni*16 + ll;
                    f32x4 v = acc[mi][ni];
                    *(ushort4*)(smq + srow_b(nd, f0)) = pack4(
                        fmaxf(v[0]+bi.x,0.f), fmaxf(v[1]+bi.y,0.f),
                        fmaxf(v[2]+bi.z,0.f), fmaxf(v[3]+bi.w,0.f));
                }
            }
            __syncthreads();
        }

        // ---------- S3: H = relu(T @ w2 + b2) : Srow -> Srow (in-place)
        {
            f32x4 acc[4][4];
            #pragma unroll
            for (int i=0;i<4;++i){
                #pragma unroll
                for (int j=0;j<4;++j) acc[i][j] = zero4;
            }
            const u16* chw = wb_w2 + ((w4*2)<<10) + ll*32 + lgp*8;
            #pragma unroll
            for (int t=0;t<8;++t){
                const u16* ct = chw + t*8192;
                const int k0 = t*32 + lgp*8;
                bf16x8 cw0 = *(const bf16x8*)(ct + wfrag_off(0));
                bf16x8 cw1 = *(const bf16x8*)(ct + wfrag_off(1));
                bf16x8 cw2 = *(const bf16x8*)(ct + wfrag_off(2));
                bf16x8 cw3 = *(const bf16x8*)(ct + wfrag_off(3));
                bf16x8 b[4];
                #pragma unroll
                for (int ni=0;ni<4;++ni) b[ni] = *(const bf16x8*)(smq + srow_b(ni*16+ll, k0));
                #pragma unroll
                for (int ni=0;ni<4;++ni){
                    acc[0][ni] = __builtin_amdgcn_mfma_f32_16x16x32_bf16(cw0, b[ni], acc[0][ni],0,0,0);
                    acc[1][ni] = __builtin_amdgcn_mfma_f32_16x16x32_bf16(cw1, b[ni], acc[1][ni],0,0,0);
                    acc[2][ni] = __builtin_amdgcn_mfma_f32_16x16x32_bf16(cw2, b[ni], acc[2][ni],0,0,0);
                    acc[3][ni] = __builtin_amdgcn_mfma_f32_16x16x32_bf16(cw3, b[ni], acc[3][ni],0,0,0);
                }
            }
            __syncthreads();   // all waves done reading Srow before overwrite
            #pragma unroll
            for (int mi=0;mi<4;++mi){
                int f0 = slab + mi*16 + lgp*4;
                float4 bi = *(const float4*)(b2 + f0);
                #pragma unroll
                for (int ni=0;ni<4;++ni){
                    int nd = ni*16 + ll;
                    f32x4 v = acc[mi][ni];
                    *(ushort4*)(smq + srow_b(nd, f0)) = pack4(
                        fmaxf(v[0]+bi.x,0.f), fmaxf(v[1]+bi.y,0.f),
                        fmaxf(v[2]+bi.z,0.f), fmaxf(v[3]+bi.w,0.f));
                }
            }
            __syncthreads();
        }

        // ---------- S4: attention (U in registers; logits -> softmax -> pool)
        {
            f32x4 acc[4][4];
            #pragma unroll
            for (int i=0;i<4;++i){
                #pragma unroll
                for (int j=0;j<4;++j) acc[i][j] = zero4;
            }
            const u16* chw = wb_aw + ((w4*2)<<10) + ll*32 + lgp*8;
            #pragma unroll
            for (int t=0;t<8;++t){
                const u16* ct = chw + t*8192;
                const int k0 = t*32 + lgp*8;
                bf16x8 cw0 = *(const bf16x8*)(ct + wfrag_off(0));
                bf16x8 cw1 = *(const bf16x8*)(ct + wfrag_off(1));
                bf16x8 cw2 = *(const bf16x8*)(ct + wfrag_off(2));
                bf16x8 cw3 = *(const bf16x8*)(ct + wfrag_off(3));
                bf16x8 a[4];
                #pragma unroll
                for (int mi=0;mi<4;++mi) a[mi] = *(const bf16x8*)(smq + srow_b(mi*16+ll, k0));
                #pragma unroll
                for (int mi=0;mi<4;++mi){
                    acc[mi][0] = __builtin_amdgcn_mfma_f32_16x16x32_bf16(a[mi], cw0, acc[mi][0],0,0,0);
                    acc[mi][1] = __builtin_amdgcn_mfma_f32_16x16x32_bf16(a[mi], cw1, acc[mi][1],0,0,0);
                    acc[mi][2] = __builtin_amdgcn_mfma_f32_16x16x32_bf16(a[mi], cw2, acc[mi][2],0,0,0);
                    acc[mi][3] = __builtin_amdgcn_mfma_f32_16x16x32_bf16(a[mi], cw3, acc[mi][3],0,0,0);
                }
            }
            float abv[4], avv[4];
            #pragma unroll
            for (int ni=0;ni<4;++ni){
                int c = slab + ni*16 + ll;
                abv[ni] = ab[c]; avv[ni] = av[c];
            }
            float lgt[4][4];
            #pragma unroll
            for (int mi=0;mi<4;++mi){
                #pragma unroll
                for (int r=0;r<4;++r) lgt[mi][r] = 0.f;
            }
            #pragma unroll
            for (int mi=0;mi<4;++mi){
                #pragma unroll
                for (int ni=0;ni<4;++ni){
                    f32x4 v = acc[mi][ni];
                    #pragma unroll
                    for (int r=0;r<4;++r) lgt[mi][r] += fmaxf(v[r]+abv[ni],0.f)*avv[ni];
                }
            }
            #pragma unroll
            for (int mi=0;mi<4;++mi){
                #pragma unroll
                for (int r=0;r<4;++r){
                    float vv = lgt[mi][r];
                    vv += __shfl_xor(vv,1,64); vv += __shfl_xor(vv,2,64);
                    vv += __shfl_xor(vv,4,64); vv += __shfl_xor(vv,8,64);
                    lgt[mi][r] = vv;
                }
            }
            float* red = (float*)(smq + SCOL_OFF);
            if (ll == 0){
                #pragma unroll
                for (int mi=0;mi<4;++mi){
                    #pragma unroll
                    for (int r=0;r<4;++r){
                        int node = mi*16 + lgp*4 + r;
                        red[w4*64 + node] = lgt[mi][r];
                    }
                }
            }
            __syncthreads();
            if (tid < 128){
                int qs = tid >> 6, t64 = tid & 63;
                const float* rq = (const float*)(sm + qs*65536 + SCOL_OFF);
                float lv = rq[t64] + rq[64+t64] + rq[128+t64] + rq[192+t64];
                float v = (t64 < 63) ? lv : -INFINITY;
                float m = v;
                #pragma unroll
                for (int off=32; off; off>>=1) m = fmaxf(m, __shfl_xor(m, off, 64));
                float e = (t64 < 63) ? expf(v - m) : 0.f;
                float s = e;
                #pragma unroll
                for (int off=32; off; off>>=1) s += __shfl_xor(s, off, 64);
                *(float*)(sm + qs*65536 + SCOL_OFF + 1024 + t64*4) = e / s;
            }
            __syncthreads();
            {
                int qs = tid >> 8, c = tid & 255;
                char* smr = sm + qs*65536;
                const float* alpha = (const float*)(smr + SCOL_OFF + 1024);
                float pool = 0.f;
                for (int r=0;r<63;++r)
                    pool += alpha[r]*b2f(*(const u16*)(smr + srow_b(r,c)));
                long zb0 = ((long)blockIdx.x*2 + qs)*1024 + zoff;
                zb[zb0 + c]       = f2b(pool);
                zb[zb0 + 256 + c] = *(const u16*)(smr + srow_b(63,c));
            }
            __syncthreads();
        }

        // ---------- S5 (layer 0 only): P1 = H1 @ w1b : Srow -> Scol
        if (layer == 0){
            f32x4 acc[4][4];
            #pragma unroll
            for (int i=0;i<4;++i){
                #pragma unroll
                for (int j=0;j<4;++j) acc[i][j] = zero4;
            }
            const u16* chw = wb_w1b + ((w4*2)<<10) + ll*32 + lgp*8;
            #pragma unroll
            for (int t=0;t<8;++t){
                const u16* ct = chw + t*8192;
                const int k0 = t*32 + lgp*8;
                bf16x8 cw0 = *(const bf16x8*)(ct + wfrag_off(0));
                bf16x8 cw1 = *(const bf16x8*)(ct + wfrag_off(1));
                bf16x8 cw2 = *(const bf16x8*)(ct + wfrag_off(2));
                bf16x8 cw3 = *(const bf16x8*)(ct + wfrag_off(3));
                bf16x8 a[4];
                #pragma unroll
                for (int mi=0;mi<4;++mi) a[mi] = *(const bf16x8*)(smq + srow_b(mi*16+ll, k0));
                #pragma unroll
                for (int mi=0;mi<4;++mi){
                    acc[mi][0] = __builtin_amdgcn_mfma_f32_16x16x32_bf16(a[mi], cw0, acc[mi][0],0,0,0);
                    acc[mi][1] = __builtin_amdgcn_mfma_f32_16x16x32_bf16(a[mi], cw1, acc[mi][1],0,0,0);
                    acc[mi][2] = __builtin_amdgcn_mfma_f32_16x16x32_bf16(a[mi], cw2, acc[mi][2],0,0,0);
                    acc[mi][3] = __builtin_amdgcn_mfma_f32_16x16x32_bf16(a[mi], cw3, acc[mi][3],0,0,0);
                }
            }
            __syncthreads();   // softmax-scratch reads done before Scol overwrite
            #pragma unroll
            for (int mi=0;mi<4;++mi){
                #pragma unroll
                for (int ni=0;ni<4;++ni){
                    int fo = slab + ni*16 + ll, nd0 = mi*16 + lgp*4;
                    f32x4 v = acc[mi][ni];
                    *(ushort4*)(smq + scol_b(fo,nd0)) = pack4(v[0],v[1],v[2],v[3]);
                }
            }
            __syncthreads();
        }
    }
}

// ---------------------------------------------------------------------------
// E' = emb @ w1a  (50000x300 @ 300x256 -> bf16 50000x256 row-major).
// ---------------------------------------------------------------------------
__global__ __launch_bounds__(256) void eprime_k(
    const float* __restrict__ emb, const u16* __restrict__ blob,
    u16* __restrict__ eprime)
{
    __shared__ __align__(16) char sm[4096];     // 2 x 2KB A-tile dbuf
    const int h = blockIdx.x, m0 = blockIdx.y * 32;
    const int tid = threadIdx.x;
    const int w = tid>>6, l = tid&63, lgp = l>>4, ll = l&15;
    const f32x4 zero4 = {0.f,0.f,0.f,0.f};
    const int slab = h*4 + w;

    const int r  = tid >> 3;          // row 0..31
    const int kc = (tid & 7) * 4;     // k-chunk (floats) within 32
    int rowg = m0 + r; if (rowg > 49999) rowg = 49999;
    const long arow = (long)rowg * 300;
    const int wbyte = (r*64 + (tid&7)*8) ^ ((r&7)<<4);

    float4 pv = (kc + 4 <= 300) ? *(const float4*)(emb + arow + kc)
                                : make_float4(0.f,0.f,0.f,0.f);
    const u16* chw = blob + (slab<<10) + ll*32 + lgp*8;
    bf16x8 w0 = *(const bf16x8*)(chw);
    bf16x8 w1 = *(const bf16x8*)(chw + 512);

    f32x4 acc[2][2];
    acc[0][0]=zero4; acc[0][1]=zero4; acc[1][0]=zero4; acc[1][1]=zero4;

    #pragma unroll
    for (int t=0;t<10;++t){
        float4 cur = pv;
        bf16x8 cw0 = w0, cw1 = w1;
        if (t < 9){
            int kn = (t+1)*32 + kc;
            pv = (kn + 4 <= 300) ? *(const float4*)(emb + arow + kn)
                                 : make_float4(0.f,0.f,0.f,0.f);
            const u16* nx = chw + (t+1)*8192;
            w0 = *(const bf16x8*)(nx);
            w1 = *(const bf16x8*)(nx + 512);
        }
        *(ushort4*)(sm + (t&1)*2048 + wbyte) = pack4(cur.x,cur.y,cur.z,cur.w);
        __syncthreads();
        const char* eb = sm + (t&1)*2048;
        bf16x8 a0, a1;
        {
            int row = ll;
            a0 = *(const bf16x8*)(eb + ((row*64 + lgp*16) ^ ((row&7)<<4)));
            row = 16 + ll;
            a1 = *(const bf16x8*)(eb + ((row*64 + lgp*16) ^ ((row&7)<<4)));
        }
        acc[0][0] = __builtin_amdgcn_mfma_f32_16x16x32_bf16(a0, cw0, acc[0][0],0,0,0);
        acc[0][1] = __builtin_amdgcn_mfma_f32_16x16x32_bf16(a0, cw1, acc[0][1],0,0,0);
        acc[1][0] = __builtin_amdgcn_mfma_f32_16x16x32_bf16(a1, cw0, acc[1][0],0,0,0);
        acc[1][1] = __builtin_amdgcn_mfma_f32_16x16x32_bf16(a1, cw1, acc[1][1],0,0,0);
        __syncthreads();
    }
    #pragma unroll
    for (int mi=0;mi<2;++mi){
        #pragma unroll
        for (int ni=0;ni<2;++ni){
            int col = h*128 + w*32 + ni*16 + ll;
            f32x4 v = acc[mi][ni];
            #pragma unroll
            for (int rr=0;rr<4;++rr){
                int row = m0 + mi*16 + lgp*4 + rr;
                if (row < 50000) eprime[(long)row*256 + col] = f2b(v[rr]);
            }
        }
    }
}

// ---------------------------------------------------------------------------
// Weight pre-pass: 6 GEMM weights -> bf16 8-slab K-tiled blobs (zero-pad K).
// ---------------------------------------------------------------------------
__global__ __launch_bounds__(256) void conv_all_k(
    const float* __restrict__ w1a, const float* __restrict__ w2a,
    const float* __restrict__ awa, const float* __restrict__ w1b,
    const float* __restrict__ w2b, const float* __restrict__ awb,
    u16* __restrict__ dst_base)
{
    long idx = (long)blockIdx.x*256 + threadIdx.x;
    if (idx >= 81920L + 5L*65536L) return;
    const float* src; u16* dst; int Ksrc; long rem;
    if (idx < 81920L){ src = w1a; dst = dst_base; Ksrc = 300; rem = idx; }
    else {
        long j = (idx - 81920L) / 65536L, r2 = (idx - 81920L) % 65536L;
        src = (j==0)?w2a:(j==1)?awa:(j==2)?w1b:(j==3)?w2b:awb;
        dst = dst_base + 81920L + j*65536L; Ksrc = 256; rem = r2;
    }
    int k = (int)(rem >> 8), n = (int)(rem & 255);
    float v = (k < Ksrc) ? src[k*256 + n] : 0.f;
    int t = k>>5, kk = k&31;
    dst[((t*8 + (n>>5))<<10) + (n&31)*32 + kk] = f2b(v);
}

// adj f32 -> bf16 (linear copy)
__global__ __launch_bounds__(256) void adjconv_k(
    const float* __restrict__ adj, u16* __restrict__ adjb)
{
    long i = (long)blockIdx.x*256 + threadIdx.x;
    if (i < 2048L*4096L) adjb[i] = f2b(adj[i]);
}

// ---------------------------------------------------------------------------
// BatchNorm stats over rows of zb (2048 x 1024 bf16): scale/shift per column.
// ---------------------------------------------------------------------------
__global__ __launch_bounds__(256) void bnstats_k(
    const u16* __restrict__ zb, const float* __restrict__ gamma,
    const float* __restrict__ beta,
    float* __restrict__ scale, float* __restrict__ shift)
{
    const int tid = threadIdx.x;
    const int cl = tid & 3, ph = tid >> 2;
    const int c = blockIdx.x * 4 + cl;
    double s = 0.0, s2 = 0.0;
    #pragma unroll 8
    for (int r = ph; r < 2048; r += 64) {
        float v = b2f(zb[(long)r * 1024 + c]);
        s += v; s2 += (double)v * v;
    }
    __shared__ double ss[256], ss2[256];
    ss[tid] = s; ss2[tid] = s2;
    __syncthreads();
    for (int off = 128; off >= 4; off >>= 1){
        if (tid < off){ ss[tid] += ss[tid+off]; ss2[tid] += ss2[tid+off]; }
        __syncthreads();
    }
    if (tid < 4){
        int cc = blockIdx.x * 4 + tid;
        double mu = ss[tid] / 2048.0;
        double var = ss2[tid] / 2048.0 - mu * mu;
        float inv = (float)(1.0 / sqrt(var + 1e-5));
        float sc = gamma[cc] * inv;
        scale[cc] = sc;
        shift[cc] = beta[cc] - (float)mu * sc;
    }
}

// fc1 weight blob: W'[k][n] = scale[k]*fc1_w[k][n] -> 8-slab K-tiled bf16
__global__ __launch_bounds__(256) void wconv_fc1_k(
    const float* __restrict__ fw, const float* __restrict__ scale,
    u16* __restrict__ dst)
{
    int lin = blockIdx.x*256 + threadIdx.x;           // 262144 total
    int c = lin >> 10, t = c >> 3, s = c & 7;
    int nl = (lin >> 5) & 31, kk = lin & 31;
    int n = s*32 + nl, k = t*32 + kk;
    dst[lin] = f2b(fw[k*256 + n] * scale[k]);
}

// fc1 bias': biasp[n] = fc1_b[n] + sum_k shift[k]*fc1_w[k][n]
__global__ __launch_bounds__(256) void fusefc1_k(
    const float* __restrict__ fw, const float* __restrict__ shift,
    const float* __restrict__ fb, float* __restrict__ biasp)
{
    const int n = blockIdx.x, tid = threadIdx.x;
    float p = 0.f;
    #pragma unroll
    for (int i=0;i<4;++i){
        int k = tid + i*256;
        p += shift[k] * fw[k*256 + n];
    }
    __shared__ float red[256];
    red[tid] = p;
    __syncthreads();
    for (int off=128; off; off>>=1){
        if (tid < off) red[tid] += red[tid+off];
        __syncthreads();
    }
    if (tid == 0) biasp[n] = fb[n] + red[0];
}

// ---------------------------------------------------------------------------
// fc1 MFMA: z2 = relu(zb @ W' + biasp)  (2048x1024 @ 1024x256, bn absorbed)
// ---------------------------------------------------------------------------
__global__ __launch_bounds__(256) void fc1_mfma_k(
    const u16* __restrict__ zb, const u16* __restrict__ blob,
    const float* __restrict__ biasp, float* __restrict__ z2)
{
    __shared__ __align__(16) char sm[4096];     // 2 x 2KB A-tile dbuf
    const int h = blockIdx.x, m0 = blockIdx.y * 32;
    const int tid = threadIdx.x;
    const int w = tid>>6, l = tid&63, lgp = l>>4, ll = l&15;
    const f32x4 zero4 = {0.f,0.f,0.f,0.f};
    const int slab = h*4 + w;

    const int r  = tid >> 3;          // row 0..31
    const int kc = (tid & 7) * 4;     // k-chunk within 32
    const long arow = (long)(m0 + r) * 1024;
    const int wbyte = (r*64 + (tid&7)*8) ^ ((r&7)<<4);

    ushort4 pv = *(const ushort4*)(zb + arow + kc);
    const u16* chw = blob + (slab<<10) + ll*32 + lgp*8;
    bf16x8 w0 = *(const bf16x8*)(chw);
    bf16x8 w1 = *(const bf16x8*)(chw + 512);

    f32x4 acc[2][2];
    acc[0][0]=zero4; acc[0][1]=zero4; acc[1][0]=zero4; acc[1][1]=zero4;

    #pragma unroll 4
    for (int t=0;t<32;++t){
        ushort4 cur = pv;
        bf16x8 cw0 = w0, cw1 = w1;
        if (t < 31){
            pv = *(const ushort4*)(zb + arow + (t+1)*32 + kc);
            const u16* nx = chw + (t+1)*8192;
            w0 = *(const bf16x8*)(nx);
            w1 = *(const bf16x8*)(nx + 512);
        }
        *(ushort4*)(sm + (t&1)*2048 + wbyte) = cur;
        __syncthreads();
        const char* eb = sm + (t&1)*2048;
        bf16x8 a0, a1;
        {
            int row = ll;
            a0 = *(const bf16x8*)(eb + ((row*64 + lgp*16) ^ ((row&7)<<4)));
            row = 16 + ll;
            a1 = *(const bf16x8*)(eb + ((row*64 + lgp*16) ^ ((row&7)<<4)));
        }
        acc[0][0] = __builtin_amdgcn_mfma_f32_16x16x32_bf16(a0, cw0, acc[0][0],0,0,0);
        acc[0][1] = __builtin_amdgcn_mfma_f32_16x16x32_bf16(a0, cw1, acc[0][1],0,0,0);
        acc[1][0] = __builtin_amdgcn_mfma_f32_16x16x32_bf16(a1, cw0, acc[1][0],0,0,0);
        acc[1][1] = __builtin_amdgcn_mfma_f32_16x16x32_bf16(a1, cw1, acc[1][1],0,0,0);
        __syncthreads();
    }
    #pragma unroll
    for (int mi=0;mi<2;++mi){
        #pragma unroll
        for (int ni=0;ni<2;++ni){
            int col = h*128 + w*32 + ni*16 + ll;
            float bv = biasp[col];
            f32x4 v = acc[mi][ni];
            #pragma unroll
            for (int rr=0;rr<4;++rr){
                int row = m0 + mi*16 + lgp*4 + rr;
                z2[(long)row*256 + col] = fmaxf(v[rr] + bv, 0.f);
            }
        }
    }
}

// ---------------------------------------------------------------------------
// Segment attention + final head fused:
// z2 (128 x 16 x 256) -> pooled -> relu(@fc2+b2) -> @fc3+b3 -> log_softmax
// ---------------------------------------------------------------------------
__global__ __launch_bounds__(256) void sattfinal_k(
    const float* __restrict__ z2, const float* __restrict__ sw,
    const float* __restrict__ sb, const float* __restrict__ sv,
    const float* __restrict__ w2, const float* __restrict__ b2,
    const float* __restrict__ w3, const float* __restrict__ b3,
    float* __restrict__ out)
{
    const int b = blockIdx.x;
    const int tid = threadIdx.x;
    __shared__ float zs[16][256];
    for (int idx = tid; idx < 16 * 256; idx += 256) {
        int r = idx >> 8, c = idx & 255;
        zs[r][c] = z2[((long)b * 16 + r) * 256 + c];
    }
    __syncthreads();

    float acc[16] = {};
    for (int k = 0; k < 256; ++k) {
        float w = sw[k * 256 + tid];
        #pragma unroll
        for (int r = 0; r < 16; ++r) acc[r] += zs[r][k] * w;
    }
    const float sbv = sb[tid], svv = sv[tid];

    __shared__ float red[16][4];
    __shared__ float logit_s[16], alpha_s[16];
    const int warp = tid >> 6, lane = tid & 63;
    #pragma unroll
    for (int r = 0; r < 16; ++r) {
        float u = fmaxf(acc[r] + sbv, 0.f);
        float lv = u * svv;
        #pragma unroll
        for (int off = 32; off; off >>= 1) lv += __shfl_down(lv, off, 64);
        if (lane == 0) red[r][warp] = lv;
    }
    __syncthreads();
    if (tid < 16) logit_s[tid] = red[tid][0] + red[tid][1] + red[tid][2] + red[tid][3];
    __syncthreads();
    if (tid < 16) {
        float m = -INFINITY;
        #pragma unroll
        for (int i = 0; i < 16; ++i) m = fmaxf(m, logit_s[i]);
        float ssum = 0.f;
        #pragma unroll
        for (int i = 0; i < 16; ++i) ssum += expf(logit_s[i] - m);
        alpha_s[tid] = expf(logit_s[tid] - m) / ssum;
    }
    __syncthreads();
    float pacc = 0.f;
    #pragma unroll
    for (int r = 0; r < 16; ++r) pacc += alpha_s[r] * zs[r][tid];

    __shared__ float ps[256], z3s[128], z4s[10];
    ps[tid] = pacc;
    __syncthreads();
    if (tid < 128){
        float a2 = b2[tid];
        for (int k = 0; k < 256; ++k) a2 += ps[k] * w2[k * 128 + tid];
        z3s[tid] = fmaxf(a2, 0.f);
    }
    __syncthreads();
    if (tid < 10){
        float a3 = b3[tid];
        for (int k = 0; k < 128; ++k) a3 += z3s[k] * w3[k * 10 + tid];
        z4s[tid] = a3;
    }
    __syncthreads();
    if (tid < 10){
        float m = z4s[0];
        #pragma unroll
        for (int i = 1; i < 10; ++i) m = fmaxf(m, z4s[i]);
        float s = 0.f;
        #pragma unroll
        for (int i = 0; i < 10; ++i) s += expf(z4s[i] - m);
        out[b * 10 + tid] = z4s[tid] - m - logf(s);
    }
}

// ---------------------------------------------------------------------------
extern "C" void kernel_launch(void* const* d_in, const int* in_sizes, int n_in,
                              void* d_out, int out_size, void* d_ws, size_t ws_size,
                              hipStream_t stream)
{
    const int*   x      = (const int*)d_in[0];
    const float* adj    = (const float*)d_in[1];
    // d_in[2] = adj_s (unused), d_in[3]/d_in[4] = shape scalars
    const float* emb    = (const float*)d_in[5];
    const float* mp0_w1 = (const float*)d_in[6];
    const float* mp0_b1 = (const float*)d_in[7];
    const float* mp0_w2 = (const float*)d_in[8];
    const float* mp0_b2 = (const float*)d_in[9];
    const float* mp1_w1 = (const float*)d_in[10];
    const float* mp1_b1 = (const float*)d_in[11];
    const float* mp1_w2 = (const float*)d_in[12];
    const float* mp1_b2 = (const float*)d_in[13];
    const float* att0_w = (const float*)d_in[14];
    const float* att0_b = (const float*)d_in[15];
    const float* att0_v = (const float*)d_in[16];
    const float* att1_w = (const float*)d_in[17];
    const float* att1_b = (const float*)d_in[18];
    const float* att1_v = (const float*)d_in[19];
    const float* bn_g   = (const float*)d_in[20];
    const float* bn_b   = (const float*)d_in[21];
    const float* fc1_w  = (const float*)d_in[22];
    const float* fc1_b  = (const float*)d_in[23];
    const float* satt_w = (const float*)d_in[24];
    const float* satt_b = (const float*)d_in[25];
    const float* satt_v = (const float*)d_in[26];
    const float* fc2_w  = (const float*)d_in[27];
    const float* fc2_b  = (const float*)d_in[28];
    const float* fc3_w  = (const float*)d_in[29];
    const float* fc3_b  = (const float*)d_in[30];
    float* out = (float*)d_out;

    float* ws = (float*)d_ws;
    float* z2      = ws;                    // 2048*256 f32
    float* scale   = z2 + 2048L * 256;      // 1024
    float* shiftv  = scale + 1024;          // 1024
    float* biasp   = shiftv + 1024;         // 256
    u16*   wbase   = (u16*)(biasp + 256);
    u16* wb_w1a  = wbase;                   // 81920 u16 (K=320 tiled)
    u16* wb_w2a  = wb_w1a + 81920;          // 65536 each below
    u16* wb_awa  = wb_w2a + 65536;
    u16* wb_w1b  = wb_awa + 65536;
    u16* wb_w2b  = wb_w1b + 65536;
    u16* wb_awb  = wb_w2b + 65536;
    u16* adjb    = wb_awb + 65536;          // 2048*4096 u16 (16.8 MB)
    u16* zb      = adjb + 2048L*4096;       // 2048*1024 u16 (4.2 MB)
    u16* fc1blob = zb + 2048L*1024;         // 262144 u16
    u16* eprime  = fc1blob + 262144;        // 50048*256 u16 (25.6 MB)
    // total ws ~ 50 MB

    conv_all_k<<<dim3(1600), dim3(256), 0, stream>>>(
        mp0_w1, mp0_w2, att0_w, mp1_w1, mp1_w2, att1_w, wbase);
    adjconv_k<<<dim3(32768), dim3(256), 0, stream>>>(adj, adjb);
    eprime_k<<<dim3(2, 1563), dim3(256), 0, stream>>>(emb, wb_w1a, eprime);

    mega_k<<<dim3(1024), dim3(512), 0, stream>>>(
        x, adjb, eprime,
        wb_w2a, wb_awa, wb_w1b, wb_w2b, wb_awb,
        mp0_b1, mp0_b2, att0_b, att0_v,
        mp1_b1, mp1_b2, att1_b, att1_v, zb);

    bnstats_k<<<dim3(256), dim3(256), 0, stream>>>(zb, bn_g, bn_b, scale, shiftv);
    wconv_fc1_k<<<dim3(1024), dim3(256), 0, stream>>>(fc1_w, scale, fc1blob);
    fusefc1_k<<<dim3(256), dim3(256), 0, stream>>>(fc1_w, shiftv, fc1_b, biasp);
    fc1_mfma_k<<<dim3(2, 64), dim3(256), 0, stream>>>(zb, fc1blob, biasp, z2);
    sattfinal_k<<<dim3(128), dim3(256), 0, stream>>>(z2, satt_w, satt_b, satt_v,
        fc2_w, fc2_b, fc3_w, fc3_b, out);
}